// Round 11
// baseline (897.888 us; speedup 1.0000x reference)
//
#include <hip/hip_runtime.h>
#include <hip/hip_bf16.h>
#include <math.h>

#define EPSBN 1e-5f

typedef short short8 __attribute__((ext_vector_type(8)));
typedef short short4v __attribute__((ext_vector_type(4)));
typedef float floatx4 __attribute__((ext_vector_type(4)));

__device__ __forceinline__ float gelu_f(float x) {
    return 0.5f * x * (1.0f + erff(x * 0.70710678118654752f));
}

__device__ __forceinline__ unsigned short f2bf(float f) {
    union { float f; unsigned int u; } c; c.f = f;
    unsigned int u = c.u;
    unsigned int r = (u + 0x7FFFu + ((u >> 16) & 1u)) >> 16;   // RNE
    return (unsigned short)r;
}

__device__ __forceinline__ float bf2f(unsigned short h) {
    union { unsigned int u; float f; } c; c.u = ((unsigned int)h) << 16;
    return c.f;
}

__device__ __forceinline__ void gl16(const unsigned short* g, unsigned short* l) {
    __builtin_amdgcn_global_load_lds(
        (const __attribute__((address_space(1))) unsigned int*)g,
        (__attribute__((address_space(3))) unsigned int*)l, 16, 0, 0);
}

// ---------------- weight preps ----------------
// region weights: [G][oc][ic][3][3] fp32 -> [G][t*6+s][band4][q4][oc48][e8] bf16.
// R10: lane <-> (g,oc,ic), 9 taps read per-lane (36B line-local, L1 catches the 9x
// reuse that the old t-across-waves order re-fetched from L3/HBM). Output bit-identical.
__global__ void wprep_bf16_k(const float* __restrict__ w, unsigned short* __restrict__ wb,
                             long total) {   // total = G*192*192
    for (long i = (long)blockIdx.x * blockDim.x + threadIdx.x; i < total;
         i += (long)gridDim.x * blockDim.x) {
        int ic = (int)(i % 192);
        long t1 = i / 192;
        int oc = (int)(t1 % 192);
        long g = t1 / 192;
        const float* src = w + (size_t)i * 9;   // == (((g*192+oc)*192+ic)*9)
        int s = ic >> 5, q = (ic >> 3) & 3, e = ic & 7;
        int bnd = oc / 48, ocl = oc % 48;
        size_t ob = (size_t)g * 331776 + (size_t)s * 6144 + bnd * 1536 + q * 384 + ocl * 8 + e;
        #pragma unroll
        for (int t = 0; t < 9; t++)
            wb[ob + (size_t)t * 36864] = f2bf(src[t]);
    }
}

// downsample weights: [OC][192][2][2] fp32 -> [t4][OC][192] bf16
__global__ void wprep_tap_k(const float* __restrict__ w, unsigned short* __restrict__ wb,
                            int OC) {
    long total = (long)4 * OC * 192;
    for (long o = (long)blockIdx.x * blockDim.x + threadIdx.x; o < total;
         o += (long)gridDim.x * blockDim.x) {
        int ic = (int)(o % 192); long t0 = o / 192;
        int oc = (int)(t0 % OC); int t = (int)(t0 / OC);
        wb[o] = f2bf(w[((size_t)oc * 192 + ic) * 4 + t]);
    }
}

// conv1 weights: [192][48] -> [48][192] fp32
__global__ void wprep_wt1_k(const float* __restrict__ w, float* __restrict__ wt) {
    int o = blockIdx.x * 256 + threadIdx.x;
    if (o < 9216) {
        int oc = o % 192, k = o / 192;
        wt[o] = w[oc * 48 + k];
    }
}

// ---------------- conv1 v2: 3->192, 4x4 s4, BN+GELU, bf16 NHWC out. G=2 oc-blocking ----
// R10 model: old conv1 was LDS-issue-bound (each thread re-reads the 2688-float tile:
// 672 ds_read_b128; ~339K cyc/CU = ~141us; FMA floor 23us). v2: thread computes TWO
// oc (oc0, oc0+96) -> same LDS reads feed 2x FMAs; block = 2 output rows (two 96-thread
// halves). Per-output FMA order unchanged -> bit-identical to v1.
__global__ __launch_bounds__(192) void conv1_k(
        const float* __restrict__ x, const float* __restrict__ wt1,
        const float* __restrict__ bg, const float* __restrict__ bb,
        const float* __restrict__ bm, const float* __restrict__ bv,
        unsigned short* __restrict__ h1c) {
    __shared__ float xs[2][3][4][224];   // 43,008 B
    int b = blockIdx.x / 28, oyp = blockIdx.x % 28;
    int tid = threadIdx.x;
    for (int i = tid; i < 5376; i += 192) {
        int col = i % 224, r = (i / 224) % 4, c = (i / 896) % 3, rr = i / 2688;
        xs[rr][c][r][col] = x[(((size_t)b * 3 + c) * 224 + 4 * (2 * oyp + rr) + r) * 224 + col];
    }
    const int half = tid / 96;        // which oy row of the pair
    const int oc0 = tid % 96;         // thread covers oc0 and oc0+96
    float w[96];
    #pragma unroll
    for (int k = 0; k < 48; k++) {
        w[k]      = wt1[k * 192 + oc0];
        w[48 + k] = wt1[k * 192 + oc0 + 96];
    }
    float inv0 = bg[oc0] * rsqrtf(bv[oc0] + EPSBN);
    float bet0 = bb[oc0] - bm[oc0] * inv0;
    float inv1 = bg[oc0 + 96] * rsqrtf(bv[oc0 + 96] + EPSBN);
    float bet1 = bb[oc0 + 96] - bm[oc0 + 96] * inv1;
    const int oy = 2 * oyp + half;
    __syncthreads();
    for (int ox = 0; ox < 56; ox++) {
        float a0 = 0.f, a1 = 0.f;
        #pragma unroll
        for (int c = 0; c < 3; c++) {
            #pragma unroll
            for (int ky = 0; ky < 4; ky++) {
                float4 v = *(const float4*)&xs[half][c][ky][4 * ox];
                const float* wk0 = &w[(c * 4 + ky) * 4];
                const float* wk1 = &w[48 + (c * 4 + ky) * 4];
                a0 += v.x * wk0[0] + v.y * wk0[1] + v.z * wk0[2] + v.w * wk0[3];
                a1 += v.x * wk1[0] + v.y * wk1[1] + v.z * wk1[2] + v.w * wk1[3];
            }
        }
        size_t ob = (((size_t)b * 56 + oy) * 56 + ox) * 192;
        h1c[ob + oc0]      = f2bf(gelu_f(a0 * inv0 + bet0));
        h1c[ob + oc0 + 96] = f2bf(gelu_f(a1 * inv1 + bet1));
    }
}

// ---------------- region conv v8: LDS weight staging, barrier-free K-loop (R7/R8, proven)
// R9 ERRATA: RSTC=204 broke 16B alignment of b128 LDS ops -> ~2x LDS-pipe cost.
// RSTC stays 200; LDS strides for b128 must stay 16B-multiples.
#define RSTC 200
#define ZCELL 98
#define AW0 19800
#define AW1 25944
template<int INF32>
__global__ __launch_bounds__(256, 2) void region_stage_k(
        const void* __restrict__ inbuf, void* __restrict__ outbuf,
        const unsigned short* __restrict__ wb,
        const float* __restrict__ pg, const float* __restrict__ pb,
        const float* __restrict__ pm, const float* __restrict__ pv,
        int gw, int W) {
    __shared__ unsigned short lds[32088];   // 64,176 B -> 2 blocks/CU
    const int raw = blockIdx.x;
    const int g = (raw & 7) + 8 * (raw >> 8);
    const int bp = (raw >> 3) & 31;
    const int b0 = bp * 2;
    const int gy = g / gw, gx = g % gw;
    const int Y0 = gy * 7, X0 = gx * 7;
    const int tid = threadIdx.x;
    const int lane = tid & 63;
    const int wid = tid >> 6;
    const int quad = lane >> 4;
    const int l15 = lane & 15;

    const size_t tsz = (size_t)W * W * 192;
    const size_t slab0 = (size_t)b0 * tsz;
    const unsigned short* wbg = wb + (size_t)g * 331776;

    // prologue staging: steps 0 and 1 into W0/W1 (overlaps with tile fill)
    {
        const unsigned short* s0 = wbg + wid * 1536 + lane * 8;
        unsigned short* d0 = &lds[AW0 + wid * 1536];
        gl16(s0, d0); gl16(s0 + 512, d0 + 512); gl16(s0 + 1024, d0 + 1024);
        const unsigned short* s1 = wbg + 6144 + wid * 1536 + lane * 8;
        unsigned short* d1 = &lds[AW1 + wid * 1536];
        gl16(s1, d1); gl16(s1 + 512, d1 + 512); gl16(s1 + 1024, d1 + 1024);
    }

    // zero cell (shared OOB target)
    if (tid < 24) *(short8*)&lds[ZCELL * RSTC + tid * 8] = (short8)0;
    // interior fill, b128 per lane: 2 tiles x 49 px x 24 ch-groups, compact cells
    for (int i = tid; i < 2352; i += 256) {
        int tI = i / 1176, rem = i % 1176, p = rem / 24, ch = rem % 24;
        int y = p / 7, xx = p % 7;
        size_t poff = slab0 + (size_t)tI * tsz + ((size_t)(Y0 + y) * W + (X0 + xx)) * 192 + ch * 8;
        short8 v;
        if (INF32) {
            const float* s4 = (const float*)inbuf + poff;
            float4 a = *(const float4*)s4;
            float4 b2 = *(const float4*)(s4 + 4);
            v[0] = (short)f2bf(a.x);  v[1] = (short)f2bf(a.y);
            v[2] = (short)f2bf(a.z);  v[3] = (short)f2bf(a.w);
            v[4] = (short)f2bf(b2.x); v[5] = (short)f2bf(b2.y);
            v[6] = (short)f2bf(b2.z); v[7] = (short)f2bf(b2.w);
        } else {
            v = *(const short8*)((const unsigned short*)inbuf + poff);
        }
        *(short8*)&lds[(tI * 49 + p) * RSTC + ch * 8] = v;
    }
    __syncthreads();

    // per-lane m-frag pixel coords (per tile; same for both tiles)
    int pyv[4], pxv[4];
    #pragma unroll
    for (int f = 0; f < 4; f++) {
        int p = f * 16 + l15; if (p > 48) p = 48;
        pyv[f] = p / 7; pxv[f] = p % 7;
    }
    // B-panel read offsets (constant across steps): band=wid, [q][48oc][8]
    int wbo[3];
    #pragma unroll
    for (int nt = 0; nt < 3; nt++)
        wbo[nt] = wid * 1536 + quad * 384 + (nt * 16 + l15) * 8;

    floatx4 acc[8][3];
    #pragma unroll
    for (int m = 0; m < 8; m++)
        #pragma unroll
        for (int nt = 0; nt < 3; nt++) acc[m][nt] = (floatx4)0.f;

    // A addresses for tap t (clamp OOB -> zero cell)
    int ca[8];
#define SET_CA(TT) { const int ky = (TT) / 3, kx = (TT) % 3; \
    _Pragma("unroll") for (int f = 0; f < 4; f++) { \
        int iy = pyv[f] + ky - 1, ix = pxv[f] + kx - 1; \
        bool ok = ((unsigned)iy < 7u) && ((unsigned)ix < 7u); \
        int c0 = ok ? (iy * 7 + ix) : ZCELL; \
        ca[f] = c0 * RSTC + quad * 8; \
        ca[4 + f] = (ok ? (c0 + 49) : ZCELL) * RSTC + quad * 8; } }

#define COMPUTE(WBASE, SL) { short8 wfv[3], pfv[8]; \
    _Pragma("unroll") for (int nt = 0; nt < 3; nt++) \
        wfv[nt] = *(const short8*)&lds[(WBASE) + wbo[nt]]; \
    _Pragma("unroll") for (int m = 0; m < 8; m++) \
        pfv[m] = *(const short8*)&lds[ca[m] + (SL) * 32]; \
    _Pragma("unroll") for (int m = 0; m < 8; m++) \
        _Pragma("unroll") for (int nt = 0; nt < 3; nt++) \
            acc[m][nt] = __builtin_amdgcn_mfma_f32_16x16x32_bf16(pfv[m], wfv[nt], acc[m][nt], 0, 0, 0); }

#define STAGE(WBASE, N) { asm volatile("" ::: "memory"); \
    const unsigned short* sg = wbg + (size_t)(N) * 6144 + wid * 1536 + lane * 8; \
    unsigned short* dl = &lds[(WBASE) + wid * 1536]; \
    gl16(sg, dl); gl16(sg + 512, dl + 512); gl16(sg + 1024, dl + 1024); }

    SET_CA(0);
    int sn = 0, tn = 0;
    #pragma unroll 1
    for (int k = 0; k < 26; k++) {
        asm volatile("s_waitcnt vmcnt(3)" ::: "memory");
        COMPUTE(AW0, sn);
        STAGE(AW0, 2 * k + 2);
        asm volatile("s_waitcnt vmcnt(3)" ::: "memory");
        COMPUTE(AW1, sn + 1);
        STAGE(AW1, 2 * k + 3);
        sn += 2;
        if (sn == 6) { sn = 0; tn++; SET_CA(tn); }
    }
    // peeled final pair: steps 52 (t=8,s=4) and 53 (t=8,s=5)
    asm volatile("s_waitcnt vmcnt(0)" ::: "memory");
    COMPUTE(AW0, 4);
    COMPUTE(AW1, 5);

#undef SET_CA
#undef COMPUTE
#undef STAGE

    // epilogue: C row = pixel (f*16 + quad*4 + r), col = oc (l15).
    // region1: residual from compact LDS tile (bit-identical to h1c); region2: fp32 global.
    #pragma unroll
    for (int nt = 0; nt < 3; nt++) {
        int oc = wid * 48 + nt * 16 + l15;
        float inv = pg[g * 192 + oc] * rsqrtf(pv[g * 192 + oc] + EPSBN);
        float bet = pb[g * 192 + oc] - pm[g * 192 + oc] * inv;
        #pragma unroll
        for (int m = 0; m < 8; m++) {
            const int tI = m >> 2;
            const int f = m & 3;
            const size_t tslab = slab0 + (size_t)tI * tsz;
            unsigned short* outb = (unsigned short*)outbuf + tslab;
            const float* resf = (const float*)inbuf + tslab;
            #pragma unroll
            for (int r = 0; r < 4; r++) {
                int p = f * 16 + quad * 4 + r;
                if (p < 49) {
                    int y = p / 7, xx = p % 7;
                    size_t pix = (size_t)(Y0 + y) * W + (X0 + xx);
                    float res = INF32 ? resf[pix * 192 + oc]
                                      : bf2f(lds[(tI * 49 + p) * RSTC + oc]);
                    outb[pix * 192 + oc] = f2bf(gelu_f(acc[m][nt][r] * inv + bet) + res);
                }
            }
        }
    }
}

// ---------------- conv2 v2: 192->192, 2x2 s2, BN+GELU. 2-oy blocks (896), hoisted W ------
__global__ __launch_bounds__(256) void conv2_mfma_k(
        const unsigned short* __restrict__ h1c, const unsigned short* __restrict__ wb,
        const float* __restrict__ bg, const float* __restrict__ bb,
        const float* __restrict__ bm, const float* __restrict__ bv,
        float* __restrict__ h2c) {
    __shared__ unsigned short lds[2 * 56 * 40];   // 8,960 B
    const int b = blockIdx.x / 14;
    const int oy0 = (blockIdx.x % 14) * 2;
    const int tid = threadIdx.x;
    const int lane = tid & 63;
    const int wid = tid >> 6;
    const int quad = lane >> 4;
    const int l15 = lane & 15;

    floatx4 acc[4][3];
    #pragma unroll
    for (int mt = 0; mt < 4; mt++)
        #pragma unroll
        for (int nt = 0; nt < 3; nt++) acc[mt][nt] = (floatx4)0.f;

    for (int ky = 0; ky < 2; ky++) {
        for (int c = 0; c < 6; c++) {
            // hoisted weight loads: latency hides under fill + barriers
            short8 wpre[2][3];
            #pragma unroll
            for (int kx = 0; kx < 2; kx++) {
                const int t = ky * 2 + kx;
                #pragma unroll
                for (int nt = 0; nt < 3; nt++) {
                    int oc = wid * 48 + nt * 16 + l15;
                    wpre[kx][nt] = *(const short8*)(wb + ((size_t)(t * 192 + oc)) * 192 + c * 32 + quad * 8);
                }
            }
            __syncthreads();
            for (int i = tid; i < 896; i += 256) {
                int icq = i & 7, kx = (i >> 3) & 1, p = i >> 4;   // p 0..55
                int oy = oy0 + p / 28, ox = p % 28;
                int iy = 2 * oy + ky, ix = 2 * ox + kx;
                const unsigned short* src =
                    h1c + (((size_t)b * 56 + iy) * 56 + ix) * 192 + c * 32 + icq * 4;
                *(short4v*)(&lds[kx * 2240 + p * 40 + icq * 4]) = *(const short4v*)src;
            }
            __syncthreads();
            #pragma unroll
            for (int kx = 0; kx < 2; kx++) {
                #pragma unroll
                for (int mt = 0; mt < 4; mt++) {
                    int p = mt * 16 + l15; if (p > 55) p = 55;
                    short8 ap = *(const short8*)(&lds[kx * 2240 + p * 40 + quad * 8]);
                    #pragma unroll
                    for (int nt = 0; nt < 3; nt++)
                        acc[mt][nt] = __builtin_amdgcn_mfma_f32_16x16x32_bf16(ap, wpre[kx][nt], acc[mt][nt], 0, 0, 0);
                }
            }
        }
    }
    #pragma unroll
    for (int nt = 0; nt < 3; nt++) {
        int oc = wid * 48 + nt * 16 + l15;
        float inv = bg[oc] * rsqrtf(bv[oc] + EPSBN);
        float bet = bb[oc] - bm[oc] * inv;
        #pragma unroll
        for (int mt = 0; mt < 4; mt++) {
            #pragma unroll
            for (int r = 0; r < 4; r++) {
                int p = mt * 16 + quad * 4 + r;
                if (p < 56) {
                    int oy = oy0 + p / 28, ox = p % 28;
                    h2c[(((size_t)b * 28 + oy) * 28 + ox) * 192 + oc] = gelu_f(acc[mt][nt][r] * inv + bet);
                }
            }
        }
    }
}

// ---------------- conv3 v2: 192->768, 2x2 s2, BN. 2-oy x 3-octile blocks (1344), hoisted W
__global__ __launch_bounds__(256) void conv3_mfma_k(
        const unsigned short* __restrict__ h2b, const unsigned short* __restrict__ wb,
        const float* __restrict__ bg, const float* __restrict__ bb,
        const float* __restrict__ bm, const float* __restrict__ bv,
        float* __restrict__ out) {
    __shared__ unsigned short lds[2 * 28 * 40];   // 4,480 B
    const int bid = blockIdx.x;
    const int b = bid / 21;
    const int sy = (bid % 21) / 3;     // 0..6 -> oy rows {2sy, 2sy+1}
    const int octile = bid % 3;
    const int tid = threadIdx.x;
    const int lane = tid & 63;
    const int wid = tid >> 6;
    const int quad = lane >> 4;
    const int l15 = lane & 15;

    floatx4 acc[2][4];
    #pragma unroll
    for (int mt = 0; mt < 2; mt++)
        #pragma unroll
        for (int nt = 0; nt < 4; nt++) acc[mt][nt] = (floatx4)0.f;

    for (int ky = 0; ky < 2; ky++) {
        for (int c = 0; c < 6; c++) {
            short8 wpre[2][4];
            #pragma unroll
            for (int kx = 0; kx < 2; kx++) {
                const int t = ky * 2 + kx;
                #pragma unroll
                for (int nt = 0; nt < 4; nt++) {
                    int oc = octile * 256 + wid * 64 + nt * 16 + l15;
                    wpre[kx][nt] = *(const short8*)(wb + ((size_t)(t * 768 + oc)) * 192 + c * 32 + quad * 8);
                }
            }
            __syncthreads();
            for (int i = tid; i < 448; i += 256) {
                int icq = i & 7, kx = (i >> 3) & 1, p = i >> 4;   // p 0..27
                int oy = sy * 2 + p / 14, ox = p % 14;
                int iy = 2 * oy + ky, ix = 2 * ox + kx;
                const unsigned short* src =
                    h2b + (((size_t)b * 28 + iy) * 28 + ix) * 192 + c * 32 + icq * 4;
                *(short4v*)(&lds[kx * 1120 + p * 40 + icq * 4]) = *(const short4v*)src;
            }
            __syncthreads();
            #pragma unroll
            for (int kx = 0; kx < 2; kx++) {
                #pragma unroll
                for (int mt = 0; mt < 2; mt++) {
                    int p = mt * 16 + l15; if (p > 27) p = 27;
                    short8 ap = *(const short8*)(&lds[kx * 1120 + p * 40 + quad * 8]);
                    #pragma unroll
                    for (int nt = 0; nt < 4; nt++)
                        acc[mt][nt] = __builtin_amdgcn_mfma_f32_16x16x32_bf16(ap, wpre[kx][nt], acc[mt][nt], 0, 0, 0);
                }
            }
        }
    }
    #pragma unroll
    for (int nt = 0; nt < 4; nt++) {
        int oc = octile * 256 + wid * 64 + nt * 16 + l15;
        float inv = bg[oc] * rsqrtf(bv[oc] + EPSBN);
        float bet = bb[oc] - bm[oc] * inv;
        #pragma unroll
        for (int mt = 0; mt < 2; mt++) {
            #pragma unroll
            for (int r = 0; r < 4; r++) {
                int p = mt * 16 + quad * 4 + r;
                if (p < 28) {
                    int oy = sy * 2 + p / 14, ox = p % 14;
                    out[((size_t)b * 196 + oy * 14 + ox) * 768 + oc] = acc[mt][nt][r] * inv + bet;
                }
            }
        }
    }
}

extern "C" void kernel_launch(void* const* d_in, const int* in_sizes, int n_in,
                              void* d_out, int out_size, void* d_ws, size_t ws_size,
                              hipStream_t stream) {
    const float* x   = (const float*)d_in[0];
    const float* w1  = (const float*)d_in[1];
    const float* b1g = (const float*)d_in[2];
    const float* b1b = (const float*)d_in[3];
    const float* b1m = (const float*)d_in[4];
    const float* b1v = (const float*)d_in[5];
    const float* r1w = (const float*)d_in[6];
    const float* r1g = (const float*)d_in[7];
    const float* r1b = (const float*)d_in[8];
    const float* r1m = (const float*)d_in[9];
    const float* r1v = (const float*)d_in[10];
    const float* w2  = (const float*)d_in[11];
    const float* b2g = (const float*)d_in[12];
    const float* b2b = (const float*)d_in[13];
    const float* b2m = (const float*)d_in[14];
    const float* b2v = (const float*)d_in[15];
    const float* r2w = (const float*)d_in[16];
    const float* r2g = (const float*)d_in[17];
    const float* r2b = (const float*)d_in[18];
    const float* r2m = (const float*)d_in[19];
    const float* r2v = (const float*)d_in[20];
    const float* w3  = (const float*)d_in[21];
    const float* b3g = (const float*)d_in[22];
    const float* b3b = (const float*)d_in[23];
    const float* b3m = (const float*)d_in[24];
    const float* b3v = (const float*)d_in[25];
    float* out = (float*)d_out;

    char* ws = (char*)d_ws;
    unsigned short* h1c  = (unsigned short*)(ws + 0);            // 77,070,336  bf16 NHWC 56x56
    float*          h2c  = (float*)         (ws + 77070336UL);   // 38,535,168  fp32 NHWC 28x28
    unsigned short* h2b  = (unsigned short*)(ws + 115605504UL);  // 19,267,584  bf16 NHWC 28x28
    unsigned short* wb1  = (unsigned short*)(ws + 134873088UL);  // 42,467,328
    unsigned short* wb2r = (unsigned short*)(ws + 177340416UL);  // 10,616,832
    float*          wt1  = (float*)         (ws + 187957248UL);  //     36,864
    unsigned short* wb2c = (unsigned short*)(ws + 187994112UL);  //    294,912
    unsigned short* wb3c = (unsigned short*)(ws + 188289024UL);  //  1,179,648
    // total 189,468,672 B

    wprep_bf16_k<<<2048, 256, 0, stream>>>(r1w, wb1, (long)64 * 36864);
    wprep_bf16_k<<<2048, 256, 0, stream>>>(r2w, wb2r, (long)16 * 36864);
    wprep_tap_k<<<576, 256, 0, stream>>>(w2, wb2c, 192);
    wprep_tap_k<<<2304, 256, 0, stream>>>(w3, wb3c, 768);
    wprep_wt1_k<<<36, 256, 0, stream>>>(w1, wt1);

    conv1_k<<<64 * 28, 192, 0, stream>>>(x, wt1, b1g, b1b, b1m, b1v, h1c);
    region_stage_k<0><<<64 * 32, 256, 0, stream>>>(h1c, h1c, wb1, r1g, r1b, r1m, r1v, 8, 56);
    conv2_mfma_k<<<64 * 14, 256, 0, stream>>>(h1c, wb2c, b2g, b2b, b2m, b2v, h2c);
    region_stage_k<1><<<16 * 32, 256, 0, stream>>>(h2c, h2b, wb2r, r2g, r2b, r2m, r2v, 4, 28);
    conv3_mfma_k<<<64 * 21, 256, 0, stream>>>(h2b, wb3c, b3g, b3b, b3m, b3v, out);
}

// Round 12
// 864.308 us; speedup vs baseline: 1.0389x; 1.0389x over previous
//
#include <hip/hip_runtime.h>
#include <hip/hip_bf16.h>
#include <math.h>

#define EPSBN 1e-5f

typedef short short8 __attribute__((ext_vector_type(8)));
typedef short short4v __attribute__((ext_vector_type(4)));
typedef float floatx4 __attribute__((ext_vector_type(4)));

__device__ __forceinline__ float gelu_f(float x) {
    return 0.5f * x * (1.0f + erff(x * 0.70710678118654752f));
}

__device__ __forceinline__ unsigned short f2bf(float f) {
    union { float f; unsigned int u; } c; c.f = f;
    unsigned int u = c.u;
    unsigned int r = (u + 0x7FFFu + ((u >> 16) & 1u)) >> 16;   // RNE
    return (unsigned short)r;
}

__device__ __forceinline__ float bf2f(unsigned short h) {
    union { unsigned int u; float f; } c; c.u = ((unsigned int)h) << 16;
    return c.f;
}

__device__ __forceinline__ void gl16(const unsigned short* g, unsigned short* l) {
    __builtin_amdgcn_global_load_lds(
        (const __attribute__((address_space(1))) unsigned int*)g,
        (__attribute__((address_space(3))) unsigned int*)l, 16, 0, 0);
}

// ---------------- weight preps ----------------
// region weights: [G][oc][ic][3][3] fp32 -> [G][t*6+s][band4][q4][oc48][e8] bf16.
// R10: lane <-> (g,oc,ic), 9 taps read per-lane (36B line-local, L1 catches the 9x reuse).
__global__ void wprep_bf16_k(const float* __restrict__ w, unsigned short* __restrict__ wb,
                             long total) {   // total = G*192*192
    for (long i = (long)blockIdx.x * blockDim.x + threadIdx.x; i < total;
         i += (long)gridDim.x * blockDim.x) {
        int ic = (int)(i % 192);
        long t1 = i / 192;
        int oc = (int)(t1 % 192);
        long g = t1 / 192;
        const float* src = w + (size_t)i * 9;   // == (((g*192+oc)*192+ic)*9)
        int s = ic >> 5, q = (ic >> 3) & 3, e = ic & 7;
        int bnd = oc / 48, ocl = oc % 48;
        size_t ob = (size_t)g * 331776 + (size_t)s * 6144 + bnd * 1536 + q * 384 + ocl * 8 + e;
        #pragma unroll
        for (int t = 0; t < 9; t++)
            wb[ob + (size_t)t * 36864] = f2bf(src[t]);
    }
}

// downsample weights: [OC][192][2][2] fp32 -> [t4][OC][192] bf16
__global__ void wprep_tap_k(const float* __restrict__ w, unsigned short* __restrict__ wb,
                            int OC) {
    long total = (long)4 * OC * 192;
    for (long o = (long)blockIdx.x * blockDim.x + threadIdx.x; o < total;
         o += (long)gridDim.x * blockDim.x) {
        int ic = (int)(o % 192); long t0 = o / 192;
        int oc = (int)(t0 % OC); int t = (int)(t0 / OC);
        wb[o] = f2bf(w[((size_t)oc * 192 + ic) * 4 + t]);
    }
}

// conv1 weights: [192][48] -> [48][192] fp32
__global__ void wprep_wt1_k(const float* __restrict__ w, float* __restrict__ wt) {
    int o = blockIdx.x * 256 + threadIdx.x;
    if (o < 9216) {
        int oc = o % 192, k = o / 192;
        wt[o] = w[oc * 48 + k];
    }
}

// ---------------- conv1 v1 (REVERTED; R11's G=2 oc-blocking cost +40us at const clocks) --
__global__ __launch_bounds__(192) void conv1_k(
        const float* __restrict__ x, const float* __restrict__ wt1,
        const float* __restrict__ bg, const float* __restrict__ bb,
        const float* __restrict__ bm, const float* __restrict__ bv,
        unsigned short* __restrict__ h1c) {
    __shared__ float xs[3][4][224];
    int b = blockIdx.x / 56, oy = blockIdx.x % 56;
    int tid = threadIdx.x;
    for (int i = tid; i < 2688; i += 192) {
        int col = i % 224, r = (i / 224) % 4, c = i / 896;
        xs[c][r][col] = x[(((size_t)b * 3 + c) * 224 + 4 * oy + r) * 224 + col];
    }
    float w[48];
    #pragma unroll
    for (int k = 0; k < 48; k++) w[k] = wt1[k * 192 + tid];
    float inv = bg[tid] * rsqrtf(bv[tid] + EPSBN);
    float bet = bb[tid] - bm[tid] * inv;
    __syncthreads();
    for (int ox = 0; ox < 56; ox++) {
        float a = 0.f;
        #pragma unroll
        for (int c = 0; c < 3; c++) {
            #pragma unroll
            for (int ky = 0; ky < 4; ky++) {
                float4 v = *(const float4*)&xs[c][ky][4 * ox];
                const float* wk = &w[(c * 4 + ky) * 4];
                a += v.x * wk[0] + v.y * wk[1] + v.z * wk[2] + v.w * wk[3];
            }
        }
        h1c[(((size_t)b * 56 + oy) * 56 + ox) * 192 + tid] = f2bf(gelu_f(a * inv + bet));
    }
}

// ---------------- region conv v8: LDS weight staging, barrier-free K-loop (R7/R8, proven)
// R12: +bofs param so region1 runs as TWO 1024-block launches -> per-dispatch dur drops
// below other kernels, letting the top-5 table reveal the true second-biggest kernel.
#define RSTC 200
#define ZCELL 98
#define AW0 19800
#define AW1 25944
template<int INF32>
__global__ __launch_bounds__(256, 2) void region_stage_k(
        const void* __restrict__ inbuf, void* __restrict__ outbuf,
        const unsigned short* __restrict__ wb,
        const float* __restrict__ pg, const float* __restrict__ pb,
        const float* __restrict__ pm, const float* __restrict__ pv,
        int gw, int W, int bofs) {
    __shared__ unsigned short lds[32088];   // 64,176 B -> 2 blocks/CU
    const int raw = blockIdx.x + bofs;
    const int g = (raw & 7) + 8 * (raw >> 8);
    const int bp = (raw >> 3) & 31;
    const int b0 = bp * 2;
    const int gy = g / gw, gx = g % gw;
    const int Y0 = gy * 7, X0 = gx * 7;
    const int tid = threadIdx.x;
    const int lane = tid & 63;
    const int wid = tid >> 6;
    const int quad = lane >> 4;
    const int l15 = lane & 15;

    const size_t tsz = (size_t)W * W * 192;
    const size_t slab0 = (size_t)b0 * tsz;
    const unsigned short* wbg = wb + (size_t)g * 331776;

    // prologue staging: steps 0 and 1 into W0/W1 (overlaps with tile fill)
    {
        const unsigned short* s0 = wbg + wid * 1536 + lane * 8;
        unsigned short* d0 = &lds[AW0 + wid * 1536];
        gl16(s0, d0); gl16(s0 + 512, d0 + 512); gl16(s0 + 1024, d0 + 1024);
        const unsigned short* s1 = wbg + 6144 + wid * 1536 + lane * 8;
        unsigned short* d1 = &lds[AW1 + wid * 1536];
        gl16(s1, d1); gl16(s1 + 512, d1 + 512); gl16(s1 + 1024, d1 + 1024);
    }

    // zero cell (shared OOB target)
    if (tid < 24) *(short8*)&lds[ZCELL * RSTC + tid * 8] = (short8)0;
    // interior fill, b128 per lane: 2 tiles x 49 px x 24 ch-groups, compact cells
    for (int i = tid; i < 2352; i += 256) {
        int tI = i / 1176, rem = i % 1176, p = rem / 24, ch = rem % 24;
        int y = p / 7, xx = p % 7;
        size_t poff = slab0 + (size_t)tI * tsz + ((size_t)(Y0 + y) * W + (X0 + xx)) * 192 + ch * 8;
        short8 v;
        if (INF32) {
            const float* s4 = (const float*)inbuf + poff;
            float4 a = *(const float4*)s4;
            float4 b2 = *(const float4*)(s4 + 4);
            v[0] = (short)f2bf(a.x);  v[1] = (short)f2bf(a.y);
            v[2] = (short)f2bf(a.z);  v[3] = (short)f2bf(a.w);
            v[4] = (short)f2bf(b2.x); v[5] = (short)f2bf(b2.y);
            v[6] = (short)f2bf(b2.z); v[7] = (short)f2bf(b2.w);
        } else {
            v = *(const short8*)((const unsigned short*)inbuf + poff);
        }
        *(short8*)&lds[(tI * 49 + p) * RSTC + ch * 8] = v;
    }
    __syncthreads();

    // per-lane m-frag pixel coords (per tile; same for both tiles)
    int pyv[4], pxv[4];
    #pragma unroll
    for (int f = 0; f < 4; f++) {
        int p = f * 16 + l15; if (p > 48) p = 48;
        pyv[f] = p / 7; pxv[f] = p % 7;
    }
    // B-panel read offsets (constant across steps): band=wid, [q][48oc][8]
    int wbo[3];
    #pragma unroll
    for (int nt = 0; nt < 3; nt++)
        wbo[nt] = wid * 1536 + quad * 384 + (nt * 16 + l15) * 8;

    floatx4 acc[8][3];
    #pragma unroll
    for (int m = 0; m < 8; m++)
        #pragma unroll
        for (int nt = 0; nt < 3; nt++) acc[m][nt] = (floatx4)0.f;

    // A addresses for tap t (clamp OOB -> zero cell)
    int ca[8];
#define SET_CA(TT) { const int ky = (TT) / 3, kx = (TT) % 3; \
    _Pragma("unroll") for (int f = 0; f < 4; f++) { \
        int iy = pyv[f] + ky - 1, ix = pxv[f] + kx - 1; \
        bool ok = ((unsigned)iy < 7u) && ((unsigned)ix < 7u); \
        int c0 = ok ? (iy * 7 + ix) : ZCELL; \
        ca[f] = c0 * RSTC + quad * 8; \
        ca[4 + f] = (ok ? (c0 + 49) : ZCELL) * RSTC + quad * 8; } }

#define COMPUTE(WBASE, SL) { short8 wfv[3], pfv[8]; \
    _Pragma("unroll") for (int nt = 0; nt < 3; nt++) \
        wfv[nt] = *(const short8*)&lds[(WBASE) + wbo[nt]]; \
    _Pragma("unroll") for (int m = 0; m < 8; m++) \
        pfv[m] = *(const short8*)&lds[ca[m] + (SL) * 32]; \
    _Pragma("unroll") for (int m = 0; m < 8; m++) \
        _Pragma("unroll") for (int nt = 0; nt < 3; nt++) \
            acc[m][nt] = __builtin_amdgcn_mfma_f32_16x16x32_bf16(pfv[m], wfv[nt], acc[m][nt], 0, 0, 0); }

#define STAGE(WBASE, N) { asm volatile("" ::: "memory"); \
    const unsigned short* sg = wbg + (size_t)(N) * 6144 + wid * 1536 + lane * 8; \
    unsigned short* dl = &lds[(WBASE) + wid * 1536]; \
    gl16(sg, dl); gl16(sg + 512, dl + 512); gl16(sg + 1024, dl + 1024); }

    SET_CA(0);
    int sn = 0, tn = 0;
    #pragma unroll 1
    for (int k = 0; k < 26; k++) {
        asm volatile("s_waitcnt vmcnt(3)" ::: "memory");
        COMPUTE(AW0, sn);
        STAGE(AW0, 2 * k + 2);
        asm volatile("s_waitcnt vmcnt(3)" ::: "memory");
        COMPUTE(AW1, sn + 1);
        STAGE(AW1, 2 * k + 3);
        sn += 2;
        if (sn == 6) { sn = 0; tn++; SET_CA(tn); }
    }
    // peeled final pair: steps 52 (t=8,s=4) and 53 (t=8,s=5)
    asm volatile("s_waitcnt vmcnt(0)" ::: "memory");
    COMPUTE(AW0, 4);
    COMPUTE(AW1, 5);

#undef SET_CA
#undef COMPUTE
#undef STAGE

    // epilogue: C row = pixel (f*16 + quad*4 + r), col = oc (l15).
    // region1: residual from compact LDS tile (bit-identical to h1c); region2: fp32 global.
    #pragma unroll
    for (int nt = 0; nt < 3; nt++) {
        int oc = wid * 48 + nt * 16 + l15;
        float inv = pg[g * 192 + oc] * rsqrtf(pv[g * 192 + oc] + EPSBN);
        float bet = pb[g * 192 + oc] - pm[g * 192 + oc] * inv;
        #pragma unroll
        for (int m = 0; m < 8; m++) {
            const int tI = m >> 2;
            const int f = m & 3;
            const size_t tslab = slab0 + (size_t)tI * tsz;
            unsigned short* outb = (unsigned short*)outbuf + tslab;
            const float* resf = (const float*)inbuf + tslab;
            #pragma unroll
            for (int r = 0; r < 4; r++) {
                int p = f * 16 + quad * 4 + r;
                if (p < 49) {
                    int y = p / 7, xx = p % 7;
                    size_t pix = (size_t)(Y0 + y) * W + (X0 + xx);
                    float res = INF32 ? resf[pix * 192 + oc]
                                      : bf2f(lds[(tI * 49 + p) * RSTC + oc]);
                    outb[pix * 192 + oc] = f2bf(gelu_f(acc[m][nt][r] * inv + bet) + res);
                }
            }
        }
    }
}

// ---------------- conv2 v2: 192->192, 2x2 s2, BN+GELU. 2-oy blocks (896), hoisted W ------
__global__ __launch_bounds__(256) void conv2_mfma_k(
        const unsigned short* __restrict__ h1c, const unsigned short* __restrict__ wb,
        const float* __restrict__ bg, const float* __restrict__ bb,
        const float* __restrict__ bm, const float* __restrict__ bv,
        float* __restrict__ h2c) {
    __shared__ unsigned short lds[2 * 56 * 40];   // 8,960 B
    const int b = blockIdx.x / 14;
    const int oy0 = (blockIdx.x % 14) * 2;
    const int tid = threadIdx.x;
    const int lane = tid & 63;
    const int wid = tid >> 6;
    const int quad = lane >> 4;
    const int l15 = lane & 15;

    floatx4 acc[4][3];
    #pragma unroll
    for (int mt = 0; mt < 4; mt++)
        #pragma unroll
        for (int nt = 0; nt < 3; nt++) acc[mt][nt] = (floatx4)0.f;

    for (int ky = 0; ky < 2; ky++) {
        for (int c = 0; c < 6; c++) {
            // hoisted weight loads: latency hides under fill + barriers
            short8 wpre[2][3];
            #pragma unroll
            for (int kx = 0; kx < 2; kx++) {
                const int t = ky * 2 + kx;
                #pragma unroll
                for (int nt = 0; nt < 3; nt++) {
                    int oc = wid * 48 + nt * 16 + l15;
                    wpre[kx][nt] = *(const short8*)(wb + ((size_t)(t * 192 + oc)) * 192 + c * 32 + quad * 8);
                }
            }
            __syncthreads();
            for (int i = tid; i < 896; i += 256) {
                int icq = i & 7, kx = (i >> 3) & 1, p = i >> 4;   // p 0..55
                int oy = oy0 + p / 28, ox = p % 28;
                int iy = 2 * oy + ky, ix = 2 * ox + kx;
                const unsigned short* src =
                    h1c + (((size_t)b * 56 + iy) * 56 + ix) * 192 + c * 32 + icq * 4;
                *(short4v*)(&lds[kx * 2240 + p * 40 + icq * 4]) = *(const short4v*)src;
            }
            __syncthreads();
            #pragma unroll
            for (int kx = 0; kx < 2; kx++) {
                #pragma unroll
                for (int mt = 0; mt < 4; mt++) {
                    int p = mt * 16 + l15; if (p > 55) p = 55;
                    short8 ap = *(const short8*)(&lds[kx * 2240 + p * 40 + quad * 8]);
                    #pragma unroll
                    for (int nt = 0; nt < 3; nt++)
                        acc[mt][nt] = __builtin_amdgcn_mfma_f32_16x16x32_bf16(ap, wpre[kx][nt], acc[mt][nt], 0, 0, 0);
                }
            }
        }
    }
    #pragma unroll
    for (int nt = 0; nt < 3; nt++) {
        int oc = wid * 48 + nt * 16 + l15;
        float inv = bg[oc] * rsqrtf(bv[oc] + EPSBN);
        float bet = bb[oc] - bm[oc] * inv;
        #pragma unroll
        for (int mt = 0; mt < 4; mt++) {
            #pragma unroll
            for (int r = 0; r < 4; r++) {
                int p = mt * 16 + quad * 4 + r;
                if (p < 56) {
                    int oy = oy0 + p / 28, ox = p % 28;
                    h2c[(((size_t)b * 28 + oy) * 28 + ox) * 192 + oc] = gelu_f(acc[mt][nt][r] * inv + bet);
                }
            }
        }
    }
}

// ---------------- conv3 v2: 192->768, 2x2 s2, BN. 2-oy x 3-octile blocks (1344), hoisted W
__global__ __launch_bounds__(256) void conv3_mfma_k(
        const unsigned short* __restrict__ h2b, const unsigned short* __restrict__ wb,
        const float* __restrict__ bg, const float* __restrict__ bb,
        const float* __restrict__ bm, const float* __restrict__ bv,
        float* __restrict__ out) {
    __shared__ unsigned short lds[2 * 28 * 40];   // 4,480 B
    const int bid = blockIdx.x;
    const int b = bid / 21;
    const int sy = (bid % 21) / 3;     // 0..6 -> oy rows {2sy, 2sy+1}
    const int octile = bid % 3;
    const int tid = threadIdx.x;
    const int lane = tid & 63;
    const int wid = tid >> 6;
    const int quad = lane >> 4;
    const int l15 = lane & 15;

    floatx4 acc[2][4];
    #pragma unroll
    for (int mt = 0; mt < 2; mt++)
        #pragma unroll
        for (int nt = 0; nt < 4; nt++) acc[mt][nt] = (floatx4)0.f;

    for (int ky = 0; ky < 2; ky++) {
        for (int c = 0; c < 6; c++) {
            short8 wpre[2][4];
            #pragma unroll
            for (int kx = 0; kx < 2; kx++) {
                const int t = ky * 2 + kx;
                #pragma unroll
                for (int nt = 0; nt < 4; nt++) {
                    int oc = octile * 256 + wid * 64 + nt * 16 + l15;
                    wpre[kx][nt] = *(const short8*)(wb + ((size_t)(t * 768 + oc)) * 192 + c * 32 + quad * 8);
                }
            }
            __syncthreads();
            for (int i = tid; i < 448; i += 256) {
                int icq = i & 7, kx = (i >> 3) & 1, p = i >> 4;   // p 0..27
                int oy = sy * 2 + p / 14, ox = p % 14;
                int iy = 2 * oy + ky, ix = 2 * ox + kx;
                const unsigned short* src =
                    h2b + (((size_t)b * 28 + iy) * 28 + ix) * 192 + c * 32 + icq * 4;
                *(short4v*)(&lds[kx * 1120 + p * 40 + icq * 4]) = *(const short4v*)src;
            }
            __syncthreads();
            #pragma unroll
            for (int kx = 0; kx < 2; kx++) {
                #pragma unroll
                for (int mt = 0; mt < 2; mt++) {
                    int p = mt * 16 + l15; if (p > 27) p = 27;
                    short8 ap = *(const short8*)(&lds[kx * 1120 + p * 40 + quad * 8]);
                    #pragma unroll
                    for (int nt = 0; nt < 4; nt++)
                        acc[mt][nt] = __builtin_amdgcn_mfma_f32_16x16x32_bf16(ap, wpre[kx][nt], acc[mt][nt], 0, 0, 0);
                }
            }
        }
    }
    #pragma unroll
    for (int nt = 0; nt < 4; nt++) {
        int oc = octile * 256 + wid * 64 + nt * 16 + l15;
        float inv = bg[oc] * rsqrtf(bv[oc] + EPSBN);
        float bet = bb[oc] - bm[oc] * inv;
        #pragma unroll
        for (int mt = 0; mt < 2; mt++) {
            #pragma unroll
            for (int r = 0; r < 4; r++) {
                int p = mt * 16 + quad * 4 + r;
                if (p < 28) {
                    int oy = sy * 2 + p / 14, ox = p % 14;
                    out[((size_t)b * 196 + oy * 14 + ox) * 768 + oc] = acc[mt][nt][r] * inv + bet;
                }
            }
        }
    }
}

extern "C" void kernel_launch(void* const* d_in, const int* in_sizes, int n_in,
                              void* d_out, int out_size, void* d_ws, size_t ws_size,
                              hipStream_t stream) {
    const float* x   = (const float*)d_in[0];
    const float* w1  = (const float*)d_in[1];
    const float* b1g = (const float*)d_in[2];
    const float* b1b = (const float*)d_in[3];
    const float* b1m = (const float*)d_in[4];
    const float* b1v = (const float*)d_in[5];
    const float* r1w = (const float*)d_in[6];
    const float* r1g = (const float*)d_in[7];
    const float* r1b = (const float*)d_in[8];
    const float* r1m = (const float*)d_in[9];
    const float* r1v = (const float*)d_in[10];
    const float* w2  = (const float*)d_in[11];
    const float* b2g = (const float*)d_in[12];
    const float* b2b = (const float*)d_in[13];
    const float* b2m = (const float*)d_in[14];
    const float* b2v = (const float*)d_in[15];
    const float* r2w = (const float*)d_in[16];
    const float* r2g = (const float*)d_in[17];
    const float* r2b = (const float*)d_in[18];
    const float* r2m = (const float*)d_in[19];
    const float* r2v = (const float*)d_in[20];
    const float* w3  = (const float*)d_in[21];
    const float* b3g = (const float*)d_in[22];
    const float* b3b = (const float*)d_in[23];
    const float* b3m = (const float*)d_in[24];
    const float* b3v = (const float*)d_in[25];
    float* out = (float*)d_out;

    char* ws = (char*)d_ws;
    unsigned short* h1c  = (unsigned short*)(ws + 0);            // 77,070,336  bf16 NHWC 56x56
    float*          h2c  = (float*)         (ws + 77070336UL);   // 38,535,168  fp32 NHWC 28x28
    unsigned short* h2b  = (unsigned short*)(ws + 115605504UL);  // 19,267,584  bf16 NHWC 28x28
    unsigned short* wb1  = (unsigned short*)(ws + 134873088UL);  // 42,467,328
    unsigned short* wb2r = (unsigned short*)(ws + 177340416UL);  // 10,616,832
    float*          wt1  = (float*)         (ws + 187957248UL);  //     36,864
    unsigned short* wb2c = (unsigned short*)(ws + 187994112UL);  //    294,912
    unsigned short* wb3c = (unsigned short*)(ws + 188289024UL);  //  1,179,648
    // total 189,468,672 B

    wprep_bf16_k<<<2048, 256, 0, stream>>>(r1w, wb1, (long)64 * 36864);
    wprep_bf16_k<<<2048, 256, 0, stream>>>(r2w, wb2r, (long)16 * 36864);
    wprep_tap_k<<<576, 256, 0, stream>>>(w2, wb2c, 192);
    wprep_tap_k<<<2304, 256, 0, stream>>>(w3, wb3c, 768);
    wprep_wt1_k<<<36, 256, 0, stream>>>(w1, wt1);

    conv1_k<<<64 * 56, 192, 0, stream>>>(x, wt1, b1g, b1b, b1m, b1v, h1c);
    region_stage_k<0><<<1024, 256, 0, stream>>>(h1c, h1c, wb1, r1g, r1b, r1m, r1v, 8, 56, 0);
    region_stage_k<0><<<1024, 256, 0, stream>>>(h1c, h1c, wb1, r1g, r1b, r1m, r1v, 8, 56, 1024);
    conv2_mfma_k<<<64 * 14, 256, 0, stream>>>(h1c, wb2c, b2g, b2b, b2m, b2v, h2c);
    region_stage_k<1><<<512, 256, 0, stream>>>(h2c, h2b, wb2r, r2g, r2b, r2m, r2v, 4, 28, 0);
    conv3_mfma_k<<<64 * 21, 256, 0, stream>>>(h2b, wb3c, b3g, b3b, b3m, b3v, out);
}

// Round 14
// 697.438 us; speedup vs baseline: 1.2874x; 1.2393x over previous
//
#include <hip/hip_runtime.h>
#include <hip/hip_bf16.h>
#include <math.h>

#define EPSBN 1e-5f

typedef short short8 __attribute__((ext_vector_type(8)));
typedef short short4v __attribute__((ext_vector_type(4)));
typedef float floatx4 __attribute__((ext_vector_type(4)));

__device__ __forceinline__ float gelu_f(float x) {
    return 0.5f * x * (1.0f + erff(x * 0.70710678118654752f));
}

__device__ __forceinline__ unsigned short f2bf(float f) {
    union { float f; unsigned int u; } c; c.f = f;
    unsigned int u = c.u;
    unsigned int r = (u + 0x7FFFu + ((u >> 16) & 1u)) >> 16;   // RNE
    return (unsigned short)r;
}

__device__ __forceinline__ float bf2f(unsigned short h) {
    union { unsigned int u; float f; } c; c.u = ((unsigned int)h) << 16;
    return c.f;
}

__device__ __forceinline__ void gl16(const unsigned short* g, unsigned short* l) {
    __builtin_amdgcn_global_load_lds(
        (const __attribute__((address_space(1))) unsigned int*)g,
        (__attribute__((address_space(3))) unsigned int*)l, 16, 0, 0);
}

// ---------------- weight preps ----------------
// region weights: [G][oc][ic][3][3] fp32 -> [G][t*6+s][band4][q4][oc48][e8] bf16.
// R10: lane <-> (g,oc,ic), 9 taps read per-lane (36B line-local, L1 catches the 9x reuse).
__global__ void wprep_bf16_k(const float* __restrict__ w, unsigned short* __restrict__ wb,
                             long total) {   // total = G*192*192
    for (long i = (long)blockIdx.x * blockDim.x + threadIdx.x; i < total;
         i += (long)gridDim.x * blockDim.x) {
        int ic = (int)(i % 192);
        long t1 = i / 192;
        int oc = (int)(t1 % 192);
        long g = t1 / 192;
        const float* src = w + (size_t)i * 9;   // == (((g*192+oc)*192+ic)*9)
        int s = ic >> 5, q = (ic >> 3) & 3, e = ic & 7;
        int bnd = oc / 48, ocl = oc % 48;
        size_t ob = (size_t)g * 331776 + (size_t)s * 6144 + bnd * 1536 + q * 384 + ocl * 8 + e;
        #pragma unroll
        for (int t = 0; t < 9; t++)
            wb[ob + (size_t)t * 36864] = f2bf(src[t]);
    }
}

// downsample weights: [OC][192][2][2] fp32 -> [t4][OC][192] bf16
__global__ void wprep_tap_k(const float* __restrict__ w, unsigned short* __restrict__ wb,
                            int OC) {
    long total = (long)4 * OC * 192;
    for (long o = (long)blockIdx.x * blockDim.x + threadIdx.x; o < total;
         o += (long)gridDim.x * blockDim.x) {
        int ic = (int)(o % 192); long t0 = o / 192;
        int oc = (int)(t0 % OC); int t = (int)(t0 / OC);
        wb[o] = f2bf(w[((size_t)oc * 192 + ic) * 4 + t]);
    }
}

// conv1 weights: [192][3][4][4] fp32 -> [oc][64] bf16, K=c*16+ky*4+kx, zero-pad k>=48
__global__ void wprep_wc1_k(const float* __restrict__ w, unsigned short* __restrict__ wb) {
    int o = blockIdx.x * 256 + threadIdx.x;
    if (o < 12288) {
        int k = o & 63, oc = o >> 6;
        wb[o] = (k < 48) ? f2bf(w[oc * 48 + k]) : (unsigned short)0;
    }
}

// ---------------- conv1 v3 (MFMA): patchify GEMM M=112/block, N=192, K=48->64 ----------
// R12 measurement: conv1-v1 was 158us, VALUBusy 69%, MfmaUtil 0 -> VALU-bound on scalar
// FMAs. Stride-4 4x4 patches are NON-OVERLAPPING -> pure patchify GEMM. Block = 2 output
// rows (112 px): LDS [112][72] bf16 patch tile (stride 144B: 16B-aligned, uniform
// bank spread for b128 - R9 lesson), conv2-verified 16x16x32 MFMA addressing,
// BN+GELU epilogue. bf16 input rounding may raise absmax slightly (stated risk).
__global__ __launch_bounds__(256) void conv1_mfma_k(
        const float* __restrict__ x, const unsigned short* __restrict__ wb1c,
        const float* __restrict__ bg, const float* __restrict__ bb,
        const float* __restrict__ bm, const float* __restrict__ bv,
        unsigned short* __restrict__ h1c) {
    __shared__ unsigned short lds[112 * 72];   // 16,128 B
    const int b = blockIdx.x / 28, oyp = blockIdx.x % 28;
    const int tid = threadIdx.x;
    const int lane = tid & 63;
    const int wid = tid >> 6;
    const int quad = lane >> 4;
    const int l15 = lane & 15;

    // patch fill: (p, c, r) -> float4 load, bf16 convert
    for (int i = tid; i < 1344; i += 256) {
        int p = i / 12, j = i % 12, c = j >> 2, r = j & 3;
        int oy = 2 * oyp + p / 56, ox = p % 56;
        float4 v = *(const float4*)&x[(((size_t)b * 3 + c) * 224 + 4 * oy + r) * 224 + 4 * ox];
        short4v s;
        s[0] = (short)f2bf(v.x); s[1] = (short)f2bf(v.y);
        s[2] = (short)f2bf(v.z); s[3] = (short)f2bf(v.w);
        *(short4v*)&lds[p * 72 + c * 16 + r * 4] = s;
    }
    // zero-pad k in [48,64)
    for (int i = tid; i < 224; i += 256) {
        int p = i >> 1, h = i & 1;
        *(short8*)&lds[p * 72 + 48 + h * 8] = (short8)0;
    }
    __syncthreads();

    // weight frags (L2-resident 24KB table)
    short8 wf[2][3];
    #pragma unroll
    for (int st = 0; st < 2; st++)
        #pragma unroll
        for (int nt = 0; nt < 3; nt++) {
            int oc = wid * 48 + nt * 16 + l15;
            wf[st][nt] = *(const short8*)&wb1c[oc * 64 + st * 32 + quad * 8];
        }

    floatx4 acc[7][3];
    #pragma unroll
    for (int mt = 0; mt < 7; mt++)
        #pragma unroll
        for (int nt = 0; nt < 3; nt++) acc[mt][nt] = (floatx4)0.f;

    #pragma unroll
    for (int st = 0; st < 2; st++)
        #pragma unroll
        for (int mt = 0; mt < 7; mt++) {
            short8 ap = *(const short8*)&lds[(mt * 16 + l15) * 72 + st * 32 + quad * 8];
            #pragma unroll
            for (int nt = 0; nt < 3; nt++)
                acc[mt][nt] = __builtin_amdgcn_mfma_f32_16x16x32_bf16(ap, wf[st][nt], acc[mt][nt], 0, 0, 0);
        }

    #pragma unroll
    for (int nt = 0; nt < 3; nt++) {
        int oc = wid * 48 + nt * 16 + l15;
        float inv = bg[oc] * rsqrtf(bv[oc] + EPSBN);
        float bet = bb[oc] - bm[oc] * inv;
        #pragma unroll
        for (int mt = 0; mt < 7; mt++) {
            #pragma unroll
            for (int r = 0; r < 4; r++) {
                int p = mt * 16 + quad * 4 + r;   // 0..111, all valid
                int oy = 2 * oyp + p / 56, ox = p % 56;
                h1c[(((size_t)b * 56 + oy) * 56 + ox) * 192 + oc] = f2bf(gelu_f(acc[mt][nt][r] * inv + bet));
            }
        }
    }
}

// ---------------- region conv v8: LDS weight staging, barrier-free K-loop (R7/R8, proven)
// R12: +bofs; region1 runs as two 1024-block launches (per-kernel visibility).
#define RSTC 200
#define ZCELL 98
#define AW0 19800
#define AW1 25944
template<int INF32>
__global__ __launch_bounds__(256, 2) void region_stage_k(
        const void* __restrict__ inbuf, void* __restrict__ outbuf,
        const unsigned short* __restrict__ wb,
        const float* __restrict__ pg, const float* __restrict__ pb,
        const float* __restrict__ pm, const float* __restrict__ pv,
        int gw, int W, int bofs) {
    __shared__ unsigned short lds[32088];   // 64,176 B -> 2 blocks/CU
    const int raw = blockIdx.x + bofs;
    const int g = (raw & 7) + 8 * (raw >> 8);
    const int bp = (raw >> 3) & 31;
    const int b0 = bp * 2;
    const int gy = g / gw, gx = g % gw;
    const int Y0 = gy * 7, X0 = gx * 7;
    const int tid = threadIdx.x;
    const int lane = tid & 63;
    const int wid = tid >> 6;
    const int quad = lane >> 4;
    const int l15 = lane & 15;

    const size_t tsz = (size_t)W * W * 192;
    const size_t slab0 = (size_t)b0 * tsz;
    const unsigned short* wbg = wb + (size_t)g * 331776;

    // prologue staging: steps 0 and 1 into W0/W1 (overlaps with tile fill)
    {
        const unsigned short* s0 = wbg + wid * 1536 + lane * 8;
        unsigned short* d0 = &lds[AW0 + wid * 1536];
        gl16(s0, d0); gl16(s0 + 512, d0 + 512); gl16(s0 + 1024, d0 + 1024);
        const unsigned short* s1 = wbg + 6144 + wid * 1536 + lane * 8;
        unsigned short* d1 = &lds[AW1 + wid * 1536];
        gl16(s1, d1); gl16(s1 + 512, d1 + 512); gl16(s1 + 1024, d1 + 1024);
    }

    // zero cell (shared OOB target)
    if (tid < 24) *(short8*)&lds[ZCELL * RSTC + tid * 8] = (short8)0;
    // interior fill, b128 per lane: 2 tiles x 49 px x 24 ch-groups, compact cells
    for (int i = tid; i < 2352; i += 256) {
        int tI = i / 1176, rem = i % 1176, p = rem / 24, ch = rem % 24;
        int y = p / 7, xx = p % 7;
        size_t poff = slab0 + (size_t)tI * tsz + ((size_t)(Y0 + y) * W + (X0 + xx)) * 192 + ch * 8;
        short8 v;
        if (INF32) {
            const float* s4 = (const float*)inbuf + poff;
            float4 a = *(const float4*)s4;
            float4 b2 = *(const float4*)(s4 + 4);
            v[0] = (short)f2bf(a.x);  v[1] = (short)f2bf(a.y);
            v[2] = (short)f2bf(a.z);  v[3] = (short)f2bf(a.w);
            v[4] = (short)f2bf(b2.x); v[5] = (short)f2bf(b2.y);
            v[6] = (short)f2bf(b2.z); v[7] = (short)f2bf(b2.w);
        } else {
            v = *(const short8*)((const unsigned short*)inbuf + poff);
        }
        *(short8*)&lds[(tI * 49 + p) * RSTC + ch * 8] = v;
    }
    __syncthreads();

    // per-lane m-frag pixel coords (per tile; same for both tiles)
    int pyv[4], pxv[4];
    #pragma unroll
    for (int f = 0; f < 4; f++) {
        int p = f * 16 + l15; if (p > 48) p = 48;
        pyv[f] = p / 7; pxv[f] = p % 7;
    }
    // B-panel read offsets (constant across steps): band=wid, [q][48oc][8]
    int wbo[3];
    #pragma unroll
    for (int nt = 0; nt < 3; nt++)
        wbo[nt] = wid * 1536 + quad * 384 + (nt * 16 + l15) * 8;

    floatx4 acc[8][3];
    #pragma unroll
    for (int m = 0; m < 8; m++)
        #pragma unroll
        for (int nt = 0; nt < 3; nt++) acc[m][nt] = (floatx4)0.f;

    // A addresses for tap t (clamp OOB -> zero cell)
    int ca[8];
#define SET_CA(TT) { const int ky = (TT) / 3, kx = (TT) % 3; \
    _Pragma("unroll") for (int f = 0; f < 4; f++) { \
        int iy = pyv[f] + ky - 1, ix = pxv[f] + kx - 1; \
        bool ok = ((unsigned)iy < 7u) && ((unsigned)ix < 7u); \
        int c0 = ok ? (iy * 7 + ix) : ZCELL; \
        ca[f] = c0 * RSTC + quad * 8; \
        ca[4 + f] = (ok ? (c0 + 49) : ZCELL) * RSTC + quad * 8; } }

#define COMPUTE(WBASE, SL) { short8 wfv[3], pfv[8]; \
    _Pragma("unroll") for (int nt = 0; nt < 3; nt++) \
        wfv[nt] = *(const short8*)&lds[(WBASE) + wbo[nt]]; \
    _Pragma("unroll") for (int m = 0; m < 8; m++) \
        pfv[m] = *(const short8*)&lds[ca[m] + (SL) * 32]; \
    _Pragma("unroll") for (int m = 0; m < 8; m++) \
        _Pragma("unroll") for (int nt = 0; nt < 3; nt++) \
            acc[m][nt] = __builtin_amdgcn_mfma_f32_16x16x32_bf16(pfv[m], wfv[nt], acc[m][nt], 0, 0, 0); }

#define STAGE(WBASE, N) { asm volatile("" ::: "memory"); \
    const unsigned short* sg = wbg + (size_t)(N) * 6144 + wid * 1536 + lane * 8; \
    unsigned short* dl = &lds[(WBASE) + wid * 1536]; \
    gl16(sg, dl); gl16(sg + 512, dl + 512); gl16(sg + 1024, dl + 1024); }

    SET_CA(0);
    int sn = 0, tn = 0;
    #pragma unroll 1
    for (int k = 0; k < 26; k++) {
        asm volatile("s_waitcnt vmcnt(3)" ::: "memory");
        COMPUTE(AW0, sn);
        STAGE(AW0, 2 * k + 2);
        asm volatile("s_waitcnt vmcnt(3)" ::: "memory");
        COMPUTE(AW1, sn + 1);
        STAGE(AW1, 2 * k + 3);
        sn += 2;
        if (sn == 6) { sn = 0; tn++; SET_CA(tn); }
    }
    // peeled final pair: steps 52 (t=8,s=4) and 53 (t=8,s=5)
    asm volatile("s_waitcnt vmcnt(0)" ::: "memory");
    COMPUTE(AW0, 4);
    COMPUTE(AW1, 5);

#undef SET_CA
#undef COMPUTE
#undef STAGE

    // epilogue: C row = pixel (f*16 + quad*4 + r), col = oc (l15).
    // region1: residual from compact LDS tile (bit-identical to h1c); region2: fp32 global.
    #pragma unroll
    for (int nt = 0; nt < 3; nt++) {
        int oc = wid * 48 + nt * 16 + l15;
        float inv = pg[g * 192 + oc] * rsqrtf(pv[g * 192 + oc] + EPSBN);
        float bet = pb[g * 192 + oc] - pm[g * 192 + oc] * inv;
        #pragma unroll
        for (int m = 0; m < 8; m++) {
            const int tI = m >> 2;
            const int f = m & 3;
            const size_t tslab = slab0 + (size_t)tI * tsz;
            unsigned short* outb = (unsigned short*)outbuf + tslab;
            const float* resf = (const float*)inbuf + tslab;
            #pragma unroll
            for (int r = 0; r < 4; r++) {
                int p = f * 16 + quad * 4 + r;
                if (p < 49) {
                    int y = p / 7, xx = p % 7;
                    size_t pix = (size_t)(Y0 + y) * W + (X0 + xx);
                    float res = INF32 ? resf[pix * 192 + oc]
                                      : bf2f(lds[(tI * 49 + p) * RSTC + oc]);
                    outb[pix * 192 + oc] = f2bf(gelu_f(acc[m][nt][r] * inv + bet) + res);
                }
            }
        }
    }
}

// ---------------- conv2 v2: 192->192, 2x2 s2, BN+GELU. 2-oy blocks (896), hoisted W ------
__global__ __launch_bounds__(256) void conv2_mfma_k(
        const unsigned short* __restrict__ h1c, const unsigned short* __restrict__ wb,
        const float* __restrict__ bg, const float* __restrict__ bb,
        const float* __restrict__ bm, const float* __restrict__ bv,
        float* __restrict__ h2c) {
    __shared__ unsigned short lds[2 * 56 * 40];   // 8,960 B
    const int b = blockIdx.x / 14;
    const int oy0 = (blockIdx.x % 14) * 2;
    const int tid = threadIdx.x;
    const int lane = tid & 63;
    const int wid = tid >> 6;
    const int quad = lane >> 4;
    const int l15 = lane & 15;

    floatx4 acc[4][3];
    #pragma unroll
    for (int mt = 0; mt < 4; mt++)
        #pragma unroll
        for (int nt = 0; nt < 3; nt++) acc[mt][nt] = (floatx4)0.f;

    for (int ky = 0; ky < 2; ky++) {
        for (int c = 0; c < 6; c++) {
            // hoisted weight loads: latency hides under fill + barriers
            short8 wpre[2][3];
            #pragma unroll
            for (int kx = 0; kx < 2; kx++) {
                const int t = ky * 2 + kx;
                #pragma unroll
                for (int nt = 0; nt < 3; nt++) {
                    int oc = wid * 48 + nt * 16 + l15;
                    wpre[kx][nt] = *(const short8*)(wb + ((size_t)(t * 192 + oc)) * 192 + c * 32 + quad * 8);
                }
            }
            __syncthreads();
            for (int i = tid; i < 896; i += 256) {
                int icq = i & 7, kx = (i >> 3) & 1, p = i >> 4;   // p 0..55
                int oy = oy0 + p / 28, ox = p % 28;
                int iy = 2 * oy + ky, ix = 2 * ox + kx;
                const unsigned short* src =
                    h1c + (((size_t)b * 56 + iy) * 56 + ix) * 192 + c * 32 + icq * 4;
                *(short4v*)(&lds[kx * 2240 + p * 40 + icq * 4]) = *(const short4v*)src;
            }
            __syncthreads();
            #pragma unroll
            for (int kx = 0; kx < 2; kx++) {
                #pragma unroll
                for (int mt = 0; mt < 4; mt++) {
                    int p = mt * 16 + l15; if (p > 55) p = 55;
                    short8 ap = *(const short8*)(&lds[kx * 2240 + p * 40 + quad * 8]);
                    #pragma unroll
                    for (int nt = 0; nt < 3; nt++)
                        acc[mt][nt] = __builtin_amdgcn_mfma_f32_16x16x32_bf16(ap, wpre[kx][nt], acc[mt][nt], 0, 0, 0);
                }
            }
        }
    }
    #pragma unroll
    for (int nt = 0; nt < 3; nt++) {
        int oc = wid * 48 + nt * 16 + l15;
        float inv = bg[oc] * rsqrtf(bv[oc] + EPSBN);
        float bet = bb[oc] - bm[oc] * inv;
        #pragma unroll
        for (int mt = 0; mt < 4; mt++) {
            #pragma unroll
            for (int r = 0; r < 4; r++) {
                int p = mt * 16 + quad * 4 + r;
                if (p < 56) {
                    int oy = oy0 + p / 28, ox = p % 28;
                    h2c[(((size_t)b * 28 + oy) * 28 + ox) * 192 + oc] = gelu_f(acc[mt][nt][r] * inv + bet);
                }
            }
        }
    }
}

// ---------------- conv3 v2: 192->768, 2x2 s2, BN. 2-oy x 3-octile blocks (1344), hoisted W
__global__ __launch_bounds__(256) void conv3_mfma_k(
        const unsigned short* __restrict__ h2b, const unsigned short* __restrict__ wb,
        const float* __restrict__ bg, const float* __restrict__ bb,
        const float* __restrict__ bm, const float* __restrict__ bv,
        float* __restrict__ out) {
    __shared__ unsigned short lds[2 * 28 * 40];   // 4,480 B
    const int bid = blockIdx.x;
    const int b = bid / 21;
    const int sy = (bid % 21) / 3;     // 0..6 -> oy rows {2sy, 2sy+1}
    const int octile = bid % 3;
    const int tid = threadIdx.x;
    const int lane = tid & 63;
    const int wid = tid >> 6;
    const int quad = lane >> 4;
    const int l15 = lane & 15;

    floatx4 acc[2][4];
    #pragma unroll
    for (int mt = 0; mt < 2; mt++)
        #pragma unroll
        for (int nt = 0; nt < 4; nt++) acc[mt][nt] = (floatx4)0.f;

    for (int ky = 0; ky < 2; ky++) {
        for (int c = 0; c < 6; c++) {
            short8 wpre[2][4];
            #pragma unroll
            for (int kx = 0; kx < 2; kx++) {
                const int t = ky * 2 + kx;
                #pragma unroll
                for (int nt = 0; nt < 4; nt++) {
                    int oc = octile * 256 + wid * 64 + nt * 16 + l15;
                    wpre[kx][nt] = *(const short8*)(wb + ((size_t)(t * 768 + oc)) * 192 + c * 32 + quad * 8);
                }
            }
            __syncthreads();
            for (int i = tid; i < 448; i += 256) {
                int icq = i & 7, kx = (i >> 3) & 1, p = i >> 4;   // p 0..27
                int oy = sy * 2 + p / 14, ox = p % 14;
                int iy = 2 * oy + ky, ix = 2 * ox + kx;
                const unsigned short* src =
                    h2b + (((size_t)b * 28 + iy) * 28 + ix) * 192 + c * 32 + icq * 4;
                *(short4v*)(&lds[kx * 1120 + p * 40 + icq * 4]) = *(const short4v*)src;
            }
            __syncthreads();
            #pragma unroll
            for (int kx = 0; kx < 2; kx++) {
                #pragma unroll
                for (int mt = 0; mt < 2; mt++) {
                    int p = mt * 16 + l15; if (p > 27) p = 27;
                    short8 ap = *(const short8*)(&lds[kx * 1120 + p * 40 + quad * 8]);
                    #pragma unroll
                    for (int nt = 0; nt < 4; nt++)
                        acc[mt][nt] = __builtin_amdgcn_mfma_f32_16x16x32_bf16(ap, wpre[kx][nt], acc[mt][nt], 0, 0, 0);
                }
            }
        }
    }
    #pragma unroll
    for (int nt = 0; nt < 4; nt++) {
        int oc = octile * 256 + wid * 64 + nt * 16 + l15;
        float inv = bg[oc] * rsqrtf(bv[oc] + EPSBN);
        float bet = bb[oc] - bm[oc] * inv;
        #pragma unroll
        for (int mt = 0; mt < 2; mt++) {
            #pragma unroll
            for (int r = 0; r < 4; r++) {
                int p = mt * 16 + quad * 4 + r;
                if (p < 28) {
                    int oy = sy * 2 + p / 14, ox = p % 14;
                    out[((size_t)b * 196 + oy * 14 + ox) * 768 + oc] = acc[mt][nt][r] * inv + bet;
                }
            }
        }
    }
}

extern "C" void kernel_launch(void* const* d_in, const int* in_sizes, int n_in,
                              void* d_out, int out_size, void* d_ws, size_t ws_size,
                              hipStream_t stream) {
    const float* x   = (const float*)d_in[0];
    const float* w1  = (const float*)d_in[1];
    const float* b1g = (const float*)d_in[2];
    const float* b1b = (const float*)d_in[3];
    const float* b1m = (const float*)d_in[4];
    const float* b1v = (const float*)d_in[5];
    const float* r1w = (const float*)d_in[6];
    const float* r1g = (const float*)d_in[7];
    const float* r1b = (const float*)d_in[8];
    const float* r1m = (const float*)d_in[9];
    const float* r1v = (const float*)d_in[10];
    const float* w2  = (const float*)d_in[11];
    const float* b2g = (const float*)d_in[12];
    const float* b2b = (const float*)d_in[13];
    const float* b2m = (const float*)d_in[14];
    const float* b2v = (const float*)d_in[15];
    const float* r2w = (const float*)d_in[16];
    const float* r2g = (const float*)d_in[17];
    const float* r2b = (const float*)d_in[18];
    const float* r2m = (const float*)d_in[19];
    const float* r2v = (const float*)d_in[20];
    const float* w3  = (const float*)d_in[21];
    const float* b3g = (const float*)d_in[22];
    const float* b3b = (const float*)d_in[23];
    const float* b3m = (const float*)d_in[24];
    const float* b3v = (const float*)d_in[25];
    float* out = (float*)d_out;

    char* ws = (char*)d_ws;
    unsigned short* h1c  = (unsigned short*)(ws + 0);            // 77,070,336  bf16 NHWC 56x56
    float*          h2c  = (float*)         (ws + 77070336UL);   // 38,535,168  fp32 NHWC 28x28
    unsigned short* h2b  = (unsigned short*)(ws + 115605504UL);  // 19,267,584  bf16 NHWC 28x28
    unsigned short* wb1  = (unsigned short*)(ws + 134873088UL);  // 42,467,328
    unsigned short* wb2r = (unsigned short*)(ws + 177340416UL);  // 10,616,832
    unsigned short* wb1c = (unsigned short*)(ws + 187957248UL);  //     24,576 (bf16 conv1 W)
    unsigned short* wb2c = (unsigned short*)(ws + 187994112UL);  //    294,912
    unsigned short* wb3c = (unsigned short*)(ws + 188289024UL);  //  1,179,648
    // total 189,468,672 B

    wprep_bf16_k<<<2048, 256, 0, stream>>>(r1w, wb1, (long)64 * 36864);
    wprep_bf16_k<<<2048, 256, 0, stream>>>(r2w, wb2r, (long)16 * 36864);
    wprep_tap_k<<<576, 256, 0, stream>>>(w2, wb2c, 192);
    wprep_tap_k<<<2304, 256, 0, stream>>>(w3, wb3c, 768);
    wprep_wc1_k<<<48, 256, 0, stream>>>(w1, wb1c);

    conv1_mfma_k<<<64 * 28, 256, 0, stream>>>(x, wb1c, b1g, b1b, b1m, b1v, h1c);
    region_stage_k<0><<<1024, 256, 0, stream>>>(h1c, h1c, wb1, r1g, r1b, r1m, r1v, 8, 56, 0);
    region_stage_k<0><<<1024, 256, 0, stream>>>(h1c, h1c, wb1, r1g, r1b, r1m, r1v, 8, 56, 1024);
    conv2_mfma_k<<<64 * 14, 256, 0, stream>>>(h1c, wb2c, b2g, b2b, b2m, b2v, h2c);
    region_stage_k<1><<<512, 256, 0, stream>>>(h2c, h2b, wb2r, r2g, r2b, r2m, r2v, 4, 28, 0);
    conv3_mfma_k<<<64 * 21, 256, 0, stream>>>(h2b, wb3c, b3g, b3b, b3m, b3v, out);
}